// Round 10
// baseline (422.174 us; speedup 1.0000x reference)
//
#include <hip/hip_runtime.h>
#include <math.h>

#define EPSV 1e-6f
#define NTOK 8192
#define NE   16384
#define DIM  256
// Hard error bound of the 1-term bf16 screen: |d~ - d| <= 2*|z||e|*2^-8*1.002
// <= 0.22 for |z|<=20 (sz<=400, +6.4 sigma of chi2_256), |e|<=1.35.
// Selection margin must be >= 2B: use 0.5.
#define MARGIN 0.5f

using short8 = __attribute__((ext_vector_type(8))) short;
using f32x4v = __attribute__((ext_vector_type(4))) float;

__device__ __forceinline__ unsigned short f2bf(float v) {
    unsigned int u = __float_as_uint(v);
    u += 0x7fffu + ((u >> 16) & 1u);   // RNE
    return (unsigned short)(u >> 16);
}
__device__ __forceinline__ float bf2f(unsigned short h) {
    return __uint_as_float(((unsigned int)h) << 16);
}

__device__ __forceinline__ void gload_lds16(const void* g, void* s) {
    __builtin_amdgcn_global_load_lds(
        (const __attribute__((address_space(1))) void*)g,
        (__attribute__((address_space(3))) void*)s, 16, 0, 0);
}

// split 8 consecutive fp32 into bf16 hi/lo fragments
__device__ __forceinline__ void split8(const float4 a, const float4 b,
                                       short8& h, short8& l) {
    float f[8] = {a.x, a.y, a.z, a.w, b.x, b.y, b.z, b.w};
#pragma unroll
    for (int j = 0; j < 8; ++j) {
        unsigned short hh = f2bf(f[j]);
        h[j] = (short)hh;
        l[j] = (short)f2bf(f[j] - bf2f(hh));
    }
}

// ---------------------------------------------------------------- F0:
// blocks [0,128): z transpose + zh (bf16 hi) + per-token sz (fp64).
// blocks [128,384): emb = cb @ W.T (4-term bf16x2 MFMA, W split in-register)
// + eh (bf16 hi of emb) + se partials. zl/el no longer needed (2-phase).
__global__ __launch_bounds__(256, 2) void f0_pre(
    const float* __restrict__ zin, float* __restrict__ z_flat,
    unsigned short* __restrict__ zh, float* __restrict__ sz,
    const float* __restrict__ cb, const float* __restrict__ Wm,
    float* __restrict__ emb, unsigned short* __restrict__ eh,
    float* __restrict__ se0, float* __restrict__ se1) {
    __shared__ char smemC[65536];
    const int tid = threadIdx.x;

    if (blockIdx.x < 128) {            // ================= z path
        float (*tile)[65] = (float(*)[65])smemC;
        const int bid = blockIdx.x;
        const int yx0 = (bid & 15) * 64, b = bid >> 4;
        const int sub = tid >> 6, ln = tid & 63;
        double dacc[16];
#pragma unroll
        for (int j = 0; j < 16; ++j) dacc[j] = 0.0;

        for (int cc = 0; cc < 4; ++cc) {
            const int c0 = cc * 64;
            __syncthreads();
#pragma unroll
            for (int j = 0; j < 16; ++j) {
                int cl = j * 4 + sub;
                tile[cl][ln] = zin[((size_t)(b * 256 + c0 + cl) << 10) + yx0 + ln];
            }
            __syncthreads();
#pragma unroll
            for (int j = 0; j < 16; ++j) {
                int tl = j * 4 + sub;
                float v = tile[ln][tl];
                size_t o = (size_t)(b * 1024 + yx0 + tl) * 256 + c0 + ln;
                z_flat[o] = v;
                zh[o] = f2bf(v);
                dacc[j] += (double)v * v;
            }
        }
#pragma unroll
        for (int j = 0; j < 16; ++j) {
            double s = dacc[j];
#pragma unroll
            for (int m = 1; m < 64; m <<= 1) s += __shfl_xor(s, m);
            if (ln == 0) sz[b * 1024 + yx0 + j * 4 + sub] = (float)s;
        }
        return;
    }

    // ================= emb GEMM path
    const int bid2 = blockIdx.x - 128;
    const int w = tid >> 6, lane = tid & 63;
    const int quad = lane >> 4, lr = lane & 15;
    const int wr = w & 1, wc = w >> 1;
    const int n0 = (bid2 & 127) * 128, c0 = (bid2 >> 7) * 128;

    f32x4v acc[4][4];
#pragma unroll
    for (int mt = 0; mt < 4; ++mt)
#pragma unroll
        for (int nt = 0; nt < 4; ++nt)
            acc[mt][nt] = (f32x4v){0.f, 0.f, 0.f, 0.f};

    for (int kc = 0; kc < 4; ++kc) {
        __syncthreads();
#pragma unroll
        for (int i = 0; i < 16; ++i) {
            int s = i * 4 + w;           // wave-uniform segment 0..63
            int u = s * 64 + lane;       // global unit 0..4095
            const void* g;
            if (s < 32) {                // cbS: [kg(16)][row(128)] fp32x4
                int kg = u >> 7, row = u & 127;
                g = cb + (size_t)(n0 + row) * 256 + kc * 64 + kg * 4;
            } else {                     // wS fp32: [kg(16)][row(128)]
                int u1 = u - 2048;
                int kg = u1 >> 7, row = u1 & 127;
                g = Wm + (size_t)(c0 + row) * 256 + kc * 64 + kg * 4;
            }
            gload_lds16(g, smemC + ((size_t)u << 4));
        }
        __syncthreads();
#pragma unroll
        for (int ks = 0; ks < 2; ++ks) {
            short8 Ah[4], Al[4], Bh[4], Bl[4];
#pragma unroll
            for (int mt = 0; mt < 4; ++mt) {
                int m = wr * 64 + mt * 16 + lr;
                int kg2 = ks * 8 + quad * 2;
                float4 f0 = *(const float4*)(smemC + (((size_t)kg2 * 128 + m) << 4));
                float4 f1 = *(const float4*)(smemC + ((((size_t)kg2 + 1) * 128 + m) << 4));
                split8(f0, f1, Ah[mt], Al[mt]);
            }
#pragma unroll
            for (int nt = 0; nt < 4; ++nt) {
                int n = wc * 64 + nt * 16 + lr;
                int kg2 = ks * 8 + quad * 2;
                float4 g0 = *(const float4*)(smemC + (((size_t)(2048 + kg2 * 128 + n)) << 4));
                float4 g1 = *(const float4*)(smemC + (((size_t)(2048 + (kg2 + 1) * 128 + n)) << 4));
                split8(g0, g1, Bh[nt], Bl[nt]);
            }
#pragma unroll
            for (int mt = 0; mt < 4; ++mt)
#pragma unroll
                for (int nt = 0; nt < 4; ++nt) {
                    f32x4v a = acc[mt][nt];
                    a = __builtin_amdgcn_mfma_f32_16x16x32_bf16(Ah[mt], Bh[nt], a, 0, 0, 0);
                    a = __builtin_amdgcn_mfma_f32_16x16x32_bf16(Ah[mt], Bl[nt], a, 0, 0, 0);
                    a = __builtin_amdgcn_mfma_f32_16x16x32_bf16(Al[mt], Bh[nt], a, 0, 0, 0);
                    a = __builtin_amdgcn_mfma_f32_16x16x32_bf16(Al[mt], Bl[nt], a, 0, 0, 0);
                    acc[mt][nt] = a;
                }
        }
    }
#pragma unroll
    for (int mt = 0; mt < 4; ++mt)
#pragma unroll
        for (int rr = 0; rr < 4; ++rr) {
            int row = n0 + wr * 64 + mt * 16 + quad * 4 + rr;
#pragma unroll
            for (int nt = 0; nt < 4; ++nt) {
                int col = c0 + wc * 64 + nt * 16 + lr;
                size_t o = (size_t)row * 256 + col;
                float v = acc[mt][nt][rr];
                emb[o] = v;
                eh[o] = f2bf(v);
            }
        }
    // ---- se partial over this block's 128 cols
    __syncthreads();
    float* sblk = (float*)smemC;       // [2][128]
#pragma unroll
    for (int mt = 0; mt < 4; ++mt)
#pragma unroll
        for (int rr = 0; rr < 4; ++rr) {
            float s = 0.f;
#pragma unroll
            for (int nt = 0; nt < 4; ++nt) {
                float v = acc[mt][nt][rr];
                s = fmaf(v, v, s);
            }
#pragma unroll
            for (int st = 1; st < 16; st <<= 1) s += __shfl_xor(s, st);
            if (lr == 0)
                sblk[wc * 128 + wr * 64 + mt * 16 + quad * 4 + rr] = s;
        }
    __syncthreads();
    if (tid < 128) {
        float* sep = ((bid2 >> 7) == 0) ? se0 : se1;
        sep[n0 + tid] = sblk[tid] + sblk[128 + tid];
    }
}

// ---------------------------------------------------------------- K1 pass1:
// 1-term bf16 screen: d~ = se - 2*(zh.eh) (sz omitted — constant per row).
// Stores per-(row, 32-code chunk) minimum (cmin). No running argmin.
// R7's proven shape: 4 waves, mt=2, (256,2), 2x16KB LDS dbuf, XOR staging.
__global__ __launch_bounds__(256, 2) void k1_pass1(
    const unsigned short* __restrict__ zh, const unsigned short* __restrict__ eh,
    const float* __restrict__ se0, const float* __restrict__ se1,
    float* __restrict__ cmin) {
    __shared__ short8 smem[2][1024];   // 2 x 16 KB
    const int tid = threadIdx.x;
    const int w = tid >> 6, lane = tid & 63;
    const int quad = lane >> 4, lr = lane & 15;
    const int tokBase = blockIdx.x * 128;
    const int rowBase = tokBase + w * 32;
    const int slab = blockIdx.y;
    const int slabBase = slab * 2048;

    // A fragments (hi only): 2 mt x 8 ks = 64 VGPRs
    short8 Ah[2][8];
#pragma unroll
    for (int mt = 0; mt < 2; ++mt)
#pragma unroll
        for (int ks = 0; ks < 8; ++ks) {
            size_t o = (size_t)(rowBase + mt * 16 + lr) * 256 + ks * 32 + quad * 8;
            Ah[mt][ks] = *(const short8*)(zh + o);
        }

    // stage chunk `ch` (32 codes x 256 k, hi only = 16KB) into buffer `buf`
    auto stage = [&](int buf, int ch) {
        const int colBase = slabBase + ch * 32;
#pragma unroll
        for (int i = 0; i < 4; ++i) {
            int u = i * 256 + tid;      // 0..1023
            int col = u >> 5, kgs = u & 31;
            int kg = kgs ^ col;         // XOR swizzle
            const unsigned short* g =
                eh + (size_t)(colBase + col) * 256 + kg * 8;
            gload_lds16(g, (char*)&smem[0][0] + buf * 16384 +
                               (((size_t)i * 256 + w * 64) << 4));
        }
    };

    stage(0, 0);
    __syncthreads();

    for (int ch = 0; ch < 64; ++ch) {
        const int cur = ch & 1;
        if (ch + 1 < 64) stage(cur ^ 1, ch + 1);  // async prefetch

        const int colg0 = slabBase + ch * 32 + lr;
        const int colg1 = colg0 + 16;
        const float sec0 = se0[colg0] + se1[colg0];
        const float sec1 = se0[colg1] + se1[colg1];

        f32x4v acc[2][2];
#pragma unroll
        for (int mt = 0; mt < 2; ++mt)
#pragma unroll
            for (int nt = 0; nt < 2; ++nt)
                acc[mt][nt] = (f32x4v){0.f, 0.f, 0.f, 0.f};

#pragma unroll
        for (int ks = 0; ks < 8; ++ks) {
            short8 Bh[2];
#pragma unroll
            for (int nt = 0; nt < 2; ++nt) {
                int col = nt * 16 + lr;
                int kgs = (ks * 4 + quad) ^ col;
                Bh[nt] = smem[cur][col * 32 + kgs];
            }
#pragma unroll
            for (int mt = 0; mt < 2; ++mt)
#pragma unroll
                for (int nt = 0; nt < 2; ++nt)
                    acc[mt][nt] = __builtin_amdgcn_mfma_f32_16x16x32_bf16(
                        Ah[mt][ks], Bh[nt], acc[mt][nt], 0, 0, 0);
        }

        // chunk-min per row over the 32 cols; store to cmin
#pragma unroll
        for (int mt = 0; mt < 2; ++mt)
#pragma unroll
            for (int rr = 0; rr < 4; ++rr) {
                float d0 = fmaf(-2.0f, acc[mt][0][rr], sec0);
                float d1 = fmaf(-2.0f, acc[mt][1][rr], sec1);
                float dm = fminf(d0, d1);
#pragma unroll
                for (int st = 1; st < 16; st <<= 1)
                    dm = fminf(dm, __shfl_xor(dm, st));
                if (lr == 0)
                    cmin[(size_t)(rowBase + mt * 16 + quad * 4 + rr) * 512 +
                         slab * 64 + ch] = dm;
            }
        __syncthreads();   // prefetch landed + cur consumed
    }
}

// ---------------------------------------------------------------- K2 pass2:
// per-token (one wave each): m0 = min cmin; exact fp32 re-rank of chunks
// with cmin <= m0 + MARGIN (guaranteed to contain the argmin); then
// rotation scalars + loss partial (replaces k3a).
__global__ __launch_bounds__(256) void k2_pass2(
    const float* __restrict__ z_flat, const float* __restrict__ emb,
    const float* __restrict__ cmin, const float* __restrict__ sz,
    const float* __restrict__ se0, const float* __restrict__ se1,
    float* __restrict__ alpha, float* __restrict__ beta,
    int* __restrict__ idxf, float* __restrict__ out,
    float* __restrict__ lpart) {
    __shared__ float red[4];
    const int w = threadIdx.x >> 6, lane = threadIdx.x & 63;
    const int t = blockIdx.x * 4 + w;

    float cm[8];
#pragma unroll
    for (int r = 0; r < 8; ++r)
        cm[r] = cmin[(size_t)t * 512 + r * 64 + lane];
    float m0 = cm[0];
#pragma unroll
    for (int r = 1; r < 8; ++r) m0 = fminf(m0, cm[r]);
#pragma unroll
    for (int st = 1; st < 64; st <<= 1) m0 = fminf(m0, __shfl_xor(m0, st));
    const float thresh = m0 + MARGIN;

    const int half = lane & 1;
    const float4* zp = (const float4*)(z_flat + (size_t)t * 256 + half * 128);

    float bd = INFINITY, bdot = 0.0f;
    int bj = 0x7fffffff;

#pragma unroll 1
    for (int r = 0; r < 8; ++r) {
        unsigned long long mask = __ballot(cm[r] <= thresh);
        while (mask) {
            int src = __ffsll((unsigned long long)mask) - 1;
            mask &= mask - 1;
            int c = r * 64 + src;                      // chunk id 0..511
            int j = (c >> 6) * 2048 + (c & 63) * 32 + (lane >> 1);
            const float4* ep = (const float4*)(emb + (size_t)j * 256 + half * 128);
            float s0 = 0.f, s1 = 0.f, s2 = 0.f, s3 = 0.f;
#pragma unroll
            for (int q = 0; q < 32; q += 4) {
                float4 a0 = zp[q], a1 = zp[q + 1], a2 = zp[q + 2], a3 = zp[q + 3];
                float4 b0 = ep[q], b1 = ep[q + 1], b2 = ep[q + 2], b3 = ep[q + 3];
                s0 = fmaf(a0.x, b0.x, fmaf(a0.y, b0.y, fmaf(a0.z, b0.z, fmaf(a0.w, b0.w, s0))));
                s1 = fmaf(a1.x, b1.x, fmaf(a1.y, b1.y, fmaf(a1.z, b1.z, fmaf(a1.w, b1.w, s1))));
                s2 = fmaf(a2.x, b2.x, fmaf(a2.y, b2.y, fmaf(a2.z, b2.z, fmaf(a2.w, b2.w, s2))));
                s3 = fmaf(a3.x, b3.x, fmaf(a3.y, b3.y, fmaf(a3.z, b3.z, fmaf(a3.w, b3.w, s3))));
            }
            float sh = (s0 + s1) + (s2 + s3);
            float dot = sh + __shfl_xor(sh, 1);        // both halves
            float ses = se0[j] + se1[j];
            float d = fmaf(-2.0f, dot, ses);           // sz const per row
            if (d < bd || (d == bd && j < bj)) {
                bd = d; bj = j; bdot = dot;
            }
        }
    }
    // lexicographic (d, j) min across the wave
#pragma unroll
    for (int st = 1; st < 64; st <<= 1) {
        float od = __shfl_xor(bd, st);
        int oj = __shfl_xor(bj, st);
        float ot = __shfl_xor(bdot, st);
        if (od < bd || (od == bd && oj < bj)) { bd = od; bj = oj; bdot = ot; }
    }

    if (lane == 0) {
        const int best = bj;
        const float zes = bdot;
        const float szs = sz[t];
        const float ses = se0[best] + se1[best];
        const float sqs = szs + ses - 2.0f * zes;    // loss term (loose tol)
        float ns = sqrtf(szs), nt = sqrtf(ses);
        float inv_s = 1.0f / (ns + EPSV);
        float inv_t = 1.0f / (nt + EPSV);
        float s2 = szs * inv_s;                      // z . u
        float su = szs * inv_s * inv_s;
        float sq = ses * inv_t * inv_t;
        float uq = zes * inv_s * inv_t;
        float nw = sqrtf(su + sq + 2.0f * uq);
        float inv_w = 1.0f / (nw + EPSV);
        float s1 = (s2 + zes * inv_t) * inv_w;       // z . w_
        float scale = nt * inv_s;
        float a = scale * (1.0f - 2.0f * s1 * inv_w * inv_s);
        float bb = scale * inv_t * 2.0f * (s2 - s1 * inv_w);
        alpha[t] = a;
        beta[t] = bb;
        idxf[t] = best;
        out[2097153 + t] = (float)best;
        red[w] = sqs;
    }
    __syncthreads();
    if (threadIdx.x == 0)
        lpart[blockIdx.x] = red[0] + red[1] + red[2] + red[3];
}

// ---------------------------------------------------------------- K3b:
// Tiled z_q: coalesced emb-row gathers + LDS transpose + coalesced writes.
// Grid (128, 4). Block (0,0) also reduces the loss.
__global__ __launch_bounds__(256) void k3b_zq(
    const float* __restrict__ z_flat, const float* __restrict__ emb,
    const float* __restrict__ alpha, const float* __restrict__ beta,
    const int* __restrict__ idxf, const float* __restrict__ lpart,
    float* __restrict__ out) {
    __shared__ float Q[64][65];
    __shared__ float Asm[64], Bsm[64];
    __shared__ int Ism[64];
    const int tid = threadIdx.x;
    const int t0 = blockIdx.x * 64;
    const int c0 = blockIdx.y * 64;

    if (blockIdx.x == 0 && blockIdx.y == 0) {   // ---- loss reduction
        __shared__ float red[4];
        float s = 0.0f;
        for (int i = tid; i < 2048; i += 256) s += lpart[i];
#pragma unroll
        for (int m = 1; m < 64; m <<= 1) s += __shfl_xor(s, m);
        if ((tid & 63) == 0) red[tid >> 6] = s;
        __syncthreads();
        if (tid == 0)
            out[2097152] = 1.25f * (red[0] + red[1] + red[2] + red[3]) *
                           (1.0f / 2097152.0f);
    }

    if (tid < 64) {
        Asm[tid] = alpha[t0 + tid];
        Bsm[tid] = beta[t0 + tid];
        Ism[tid] = idxf[t0 + tid];
    }
    __syncthreads();

    const int sub = tid >> 6, ln = tid & 63;
#pragma unroll
    for (int j = 0; j < 16; ++j) {
        int tl = j * 4 + sub;
        float e = emb[(size_t)Ism[tl] * 256 + c0 + ln];
        float zv = z_flat[(size_t)(t0 + tl) * 256 + c0 + ln];
        Q[tl][ln] = Asm[tl] * zv + Bsm[tl] * e;
    }
    __syncthreads();
    const int b = t0 >> 10, yx0 = t0 & 1023;
#pragma unroll
    for (int j = 0; j < 16; ++j) {
        int cl = j * 4 + sub;
        out[((size_t)(b * 256 + c0 + cl) << 10) + yx0 + ln] = Q[ln][cl];
    }
}

// ----------------------------------------------------------------
extern "C" void kernel_launch(void* const* d_in, const int* in_sizes, int n_in,
                              void* d_out, int out_size, void* d_ws,
                              size_t ws_size, hipStream_t stream) {
    (void)in_sizes; (void)n_in; (void)out_size; (void)ws_size;
    const float* zin = (const float*)d_in[0];
    const float* cb  = (const float*)d_in[1];
    const float* Wm  = (const float*)d_in[2];
    float* out = (float*)d_out;
    char* ws = (char*)d_ws;

    float*          z_flat = (float*)(ws + 0);                     //  8 MB
    unsigned short* zh     = (unsigned short*)(ws + 8388608);      //  4 MB
    float*          emb    = (float*)(ws + 12582912);              // 16 MB
    unsigned short* eh     = (unsigned short*)(ws + 29360128);     //  8 MB
    float*          sz     = (float*)(ws + 37748736);              // 32 KB
    float*          se0    = (float*)(ws + 37781504);              // 64 KB
    float*          se1    = (float*)(ws + 37847040);              // 64 KB
    float*          cmin   = (float*)(ws + 37912576);              // 16 MB
    float*          alpha  = (float*)(ws + 54689792);              // 32 KB
    float*          beta   = (float*)(ws + 54722560);              // 32 KB
    int*            idxf   = (int*)(ws + 54755328);                // 32 KB
    float*          lpart  = (float*)(ws + 54788096);              //  8 KB

    f0_pre<<<384, 256, 0, stream>>>(zin, z_flat, zh, sz, cb, Wm,
                                    emb, eh, se0, se1);
    k1_pass1<<<dim3(64, 8), 256, 0, stream>>>(zh, eh, se0, se1, cmin);
    k2_pass2<<<2048, 256, 0, stream>>>(z_flat, emb, cmin, sz, se0, se1,
                                       alpha, beta, idxf, out, lpart);
    k3b_zq<<<dim3(128, 4), 256, 0, stream>>>(z_flat, emb, alpha, beta, idxf,
                                             lpart, out);
}